// Round 1
// baseline (3090.289 us; speedup 1.0000x reference)
//
#include <hip/hip_runtime.h>

#define NPOST 100000
#define NUSER 50000
#define NENT  20000

static __device__ __forceinline__ void atomAddF(float* p, float v){
  unsafeAtomicAdd(p, v);  // hardware global_atomic_add_f32 (device scope)
}

// ---------------- prep kernels ----------------

// B[k*64+c] = W[c*K+k]   (W is [64,K] row-major -> B is [K,64])
__global__ void k_transpose64(const float* __restrict__ W, float* __restrict__ B, int K){
  int idx = blockIdx.x * blockDim.x + threadIdx.x;
  if (idx >= K * 64) return;
  int k = idx >> 6, c = idx & 63;
  B[idx] = W[c * K + k];
}

// Bcomb[m][hk*64+c] = W_src[m, (hk/64)*64 + c, hk%64]   for m in [0,12)
__global__ void k_prep_comb(const float* __restrict__ Wsrc, float* __restrict__ Bcomb){
  int idx = blockIdx.x * blockDim.x + threadIdx.x;
  if (idx >= 12 * 8192) return;
  int m = idx >> 13;
  int rem = idx & 8191;
  int hk = rem >> 6, c = rem & 63;
  int head = hk >> 6, k = hk & 63;
  Bcomb[idx] = Wsrc[m * 8192 + (head * 64 + c) * 64 + k];
}

// weff[m][h*64+k] = sum_c W[m, h*64+c, k] * a[m, h, c]
__global__ void k_weff(const float* __restrict__ W, const float* __restrict__ a,
                       float* __restrict__ weff){
  int idx = blockIdx.x * blockDim.x + threadIdx.x;
  if (idx >= 1536) return;
  int m = idx >> 7;
  int rem = idx & 127;
  int h = rem >> 6, k = rem & 63;
  const float* Wm = W + m * 8192;
  const float* am = a + m * 128;
  float acc = 0.f;
  #pragma unroll 8
  for (int c = 0; c < 64; c++)
    acc += Wm[(h * 64 + c) * 64 + k] * am[h * 64 + c];
  weff[idx] = acc;
}

// ---------------- attention-logit kernel ----------------

static __device__ __forceinline__ void al_one(const float* __restrict__ hx,
                                              const float* __restrict__ w,
                                              float* __restrict__ out, int i){
  const float4* hr = (const float4*)(hx + (size_t)i * 64);
  const float4* w0 = (const float4*)w;
  const float4* w1 = (const float4*)(w + 64);
  float a0 = 0.f, a1 = 0.f;
  #pragma unroll
  for (int q = 0; q < 16; q++){
    float4 v = hr[q];
    float4 x0 = w0[q], x1 = w1[q];
    a0 += v.x*x0.x + v.y*x0.y + v.z*x0.z + v.w*x0.w;
    a1 += v.x*x1.x + v.y*x1.y + v.z*x1.z + v.w*x1.w;
  }
  out[i * 2]     = a0;
  out[i * 2 + 1] = a1;
}

__global__ void k_al(const float* __restrict__ hs, const float* __restrict__ ws,
                     float* __restrict__ als, int Ns,
                     const float* __restrict__ hd, const float* __restrict__ wd,
                     float* __restrict__ ald, int Nd){
  int i = blockIdx.x * blockDim.x + threadIdx.x;
  if (i < Ns) al_one(hs, ws, als, i);
  if (i < Nd) al_one(hd, wd, ald, i);
}

// ---------------- edge aggregation (one wave per edge) ----------------

__global__ __launch_bounds__(256) void k_edge(const int* __restrict__ src,
                                              const int* __restrict__ dst, int E,
                                              const float* __restrict__ hsrc,
                                              const float* __restrict__ als,
                                              const float* __restrict__ ald,
                                              float* __restrict__ agg,
                                              float* __restrict__ sden){
  int wid  = (blockIdx.x * blockDim.x + threadIdx.x) >> 6;
  int lane = threadIdx.x & 63;
  if (wid >= E) return;
  int s = src[wid];
  int d = dst[wid];
  float2 as = *(const float2*)(als + (size_t)s * 2);
  float2 ad = *(const float2*)(ald + (size_t)d * 2);
  float e0 = as.x + ad.x;
  float e1 = as.y + ad.y;
  e0 = e0 > 0.f ? e0 : 0.2f * e0;
  e1 = e1 > 0.f ? e1 : 0.2f * e1;
  float p0 = expf(e0), p1 = expf(e1);
  float hv = hsrc[(size_t)s * 64 + lane];
  atomAddF(&agg[(size_t)d * 128 + lane],      p0 * hv);
  atomAddF(&agg[(size_t)d * 128 + 64 + lane], p1 * hv);
  if (lane == 0){
    atomAddF(&sden[(size_t)d * 2],     p0);
    atomAddF(&sden[(size_t)d * 2 + 1], p1);
  }
}

// ---------------- tiled GEMM: C[N,64] (+)= prolog(A)[N,K] @ B[K,64] ----------------
// PROLOG 0: A read directly.  PROLOG 1: A = 0.5 * agg / s (per-head), K must be 128.
// BIAS: add bias[64].  ACCUM: C += result, else C = result.

template<int PROLOG, int BIAS, int ACCUM>
__global__ __launch_bounds__(256) void k_gemm64(const float* __restrict__ A,
                                                const float* __restrict__ S,
                                                const float* __restrict__ B,
                                                const float* __restrict__ bias,
                                                float* __restrict__ C, int N, int K){
  __shared__ float As[32][68];   // [k][row], padded for 16B-aligned float4 reads
  __shared__ float Bs[32][68];   // [k][col]
  int t  = threadIdx.x;
  int r0 = blockIdx.x * 64;
  int tx = t & 15, ty = t >> 4;
  float acc[4][4] = {};
  for (int k0 = 0; k0 < K; k0 += 32){
    #pragma unroll
    for (int i = 0; i < 8; i++){
      int flat = t + i * 256;          // 0..2047
      int kk = flat & 31, row = flat >> 5;
      int gr = r0 + row;
      float v = 0.f;
      if (gr < N){
        int gk = k0 + kk;
        if (PROLOG == 0){
          v = A[(size_t)gr * K + gk];
        } else {
          int head = gk >> 6;
          float sv = S[(size_t)gr * 2 + head];
          v = (sv > 0.f) ? 0.5f * A[(size_t)gr * 128 + gk] / sv : 0.f;
        }
      }
      As[kk][row] = v;
    }
    #pragma unroll
    for (int i = 0; i < 8; i++){
      int flat = t + i * 256;
      int c = flat & 63, kk = flat >> 6;
      Bs[kk][c] = B[(size_t)(k0 + kk) * 64 + c];
    }
    __syncthreads();
    #pragma unroll
    for (int kk = 0; kk < 32; kk++){
      float4 a4 = *(const float4*)&As[kk][ty * 4];
      float4 b4 = *(const float4*)&Bs[kk][tx * 4];
      float a_[4] = {a4.x, a4.y, a4.z, a4.w};
      float b_[4] = {b4.x, b4.y, b4.z, b4.w};
      #pragma unroll
      for (int i2 = 0; i2 < 4; i2++)
        #pragma unroll
        for (int j2 = 0; j2 < 4; j2++)
          acc[i2][j2] = fmaf(a_[i2], b_[j2], acc[i2][j2]);
    }
    __syncthreads();
  }
  #pragma unroll
  for (int i2 = 0; i2 < 4; i2++){
    int gr = r0 + ty * 4 + i2;
    if (gr >= N) continue;
    float4 v;
    v.x = acc[i2][0]; v.y = acc[i2][1]; v.z = acc[i2][2]; v.w = acc[i2][3];
    if (BIAS){
      float4 bb = *(const float4*)&bias[tx * 4];
      v.x += bb.x; v.y += bb.y; v.z += bb.z; v.w += bb.w;
    }
    float4* cp = (float4*)&C[(size_t)gr * 64 + tx * 4];
    if (ACCUM){
      float4 old = *cp;
      v.x += old.x; v.y += old.y; v.z += old.z; v.w += old.w;
    }
    *cp = v;
  }
}

// ---------------- bias-sum + relu ----------------

__global__ void k_bias_relu(float* __restrict__ hx, int N,
                            const float* __restrict__ b0,
                            const float* __restrict__ b1,
                            const float* __restrict__ b2){
  int i = blockIdx.x * blockDim.x + threadIdx.x;
  if (i >= N * 64) return;
  int c = i & 63;
  float bsum = b0[c];
  if (b1) bsum += b1[c];
  if (b2) bsum += b2[c];
  float v = hx[i] + bsum;
  hx[i] = v > 0.f ? v : 0.f;
}

// ---------------- classifier head ----------------

__global__ __launch_bounds__(256) void k_classifier(const float* __restrict__ hpost,
                                                    const float* __restrict__ w1,
                                                    const float* __restrict__ b1,
                                                    const float* __restrict__ w2,
                                                    const float* __restrict__ b2,
                                                    float* __restrict__ out, int N){
  __shared__ float w1s[32 * 64];
  __shared__ float b1s[32];
  __shared__ float w2s[32];
  for (int i = threadIdx.x; i < 2048; i += 256) w1s[i] = w1[i];
  if (threadIdx.x < 32){
    b1s[threadIdx.x] = b1[threadIdx.x];
    w2s[threadIdx.x] = w2[threadIdx.x];
  }
  __syncthreads();
  float bias2 = b2[0];
  for (int n = blockIdx.x * blockDim.x + threadIdx.x; n < N; n += gridDim.x * blockDim.x){
    float4 hr[16];
    const float4* hp = (const float4*)(hpost + (size_t)n * 64);
    #pragma unroll
    for (int q = 0; q < 16; q++) hr[q] = hp[q];
    float o = bias2;
    #pragma unroll 4
    for (int j = 0; j < 32; j++){
      float dacc = b1s[j];
      const float4* wr = (const float4*)(w1s + j * 64);
      #pragma unroll
      for (int q = 0; q < 16; q++){
        float4 w = wr[q]; float4 v = hr[q];
        dacc += w.x*v.x + w.y*v.y + w.z*v.z + w.w*v.w;
      }
      dacc = dacc > 0.f ? dacc : 0.f;
      o += w2s[j] * dacc;
    }
    out[n] = o;
  }
}

// ---------------- host ----------------

static inline size_t align256(size_t x){ return (x + 255) & ~(size_t)255; }

extern "C" void kernel_launch(void* const* d_in, const int* in_sizes, int n_in,
                              void* d_out, int out_size, void* d_ws, size_t ws_size,
                              hipStream_t stream){
  (void)in_sizes; (void)n_in; (void)out_size; (void)ws_size;
  const float* x_post = (const float*)d_in[0];
  const float* x_user = (const float*)d_in[1];
  const float* x_ent  = (const float*)d_in[2];
  const int* esrc[6] = {(const int*)d_in[3], (const int*)d_in[5], (const int*)d_in[7],
                        (const int*)d_in[9], (const int*)d_in[11], (const int*)d_in[13]};
  const int* edst[6] = {(const int*)d_in[4], (const int*)d_in[6], (const int*)d_in[8],
                        (const int*)d_in[10], (const int*)d_in[12], (const int*)d_in[14]};
  const float* Wp   = (const float*)d_in[15]; const float* bp = (const float*)d_in[16];
  const float* Wu   = (const float*)d_in[17]; const float* bu = (const float*)d_in[18];
  const float* We   = (const float*)d_in[19]; const float* be = (const float*)d_in[20];
  const float* Wsrc = (const float*)d_in[21];
  const float* Wdst = (const float*)d_in[22];
  const float* asrc = (const float*)d_in[23];
  const float* adst = (const float*)d_in[24];
  const float* gatb = (const float*)d_in[25];
  const float* cw1  = (const float*)d_in[26]; const float* cb1 = (const float*)d_in[27];
  const float* cw2  = (const float*)d_in[28]; const float* cb2 = (const float*)d_in[29];
  float* out = (float*)d_out;

  const int NN[3] = {NPOST, NUSER, NENT};   // type 0=post, 1=user, 2=entity

  // workspace layout (~141 MB)
  char* p = (char*)d_ws;
  auto alloc = [&](size_t bytes){ char* r = p; p += align256(bytes); return r; };
  float* hA[3]; float* hB[3];
  for (int i = 0; i < 3; i++) hA[i] = (float*)alloc((size_t)NN[i] * 64 * 4);
  for (int i = 0; i < 3; i++) hB[i] = (float*)alloc((size_t)NN[i] * 64 * 4);
  float* als    = (float*)alloc((size_t)NPOST * 2 * 4);
  float* ald    = (float*)alloc((size_t)NPOST * 2 * 4);
  float* agg    = (float*)alloc((size_t)NPOST * 128 * 4);
  float* sden   = (float*)alloc((size_t)NPOST * 2 * 4);
  float* weff_s = (float*)alloc(1536 * 4);
  float* weff_d = (float*)alloc(1536 * 4);
  float* Bpost  = (float*)alloc(768 * 64 * 4);
  float* Buser  = (float*)alloc(32 * 64 * 4);
  float* Bent   = (float*)alloc(64 * 64 * 4);
  float* Bcomb  = (float*)alloc(12 * 8192 * 4);

  // ---- weight prep ----
  k_transpose64<<<(768 * 64 + 255) / 256, 256, 0, stream>>>(Wp, Bpost, 768);
  k_transpose64<<<(32 * 64 + 255) / 256, 256, 0, stream>>>(Wu, Buser, 32);
  k_transpose64<<<(64 * 64 + 255) / 256, 256, 0, stream>>>(We, Bent, 64);
  k_prep_comb<<<(12 * 8192 + 255) / 256, 256, 0, stream>>>(Wsrc, Bcomb);
  k_weff<<<6, 256, 0, stream>>>(Wsrc, asrc, weff_s);
  k_weff<<<6, 256, 0, stream>>>(Wdst, adst, weff_d);

  // ---- input projections ----
  k_gemm64<0, 1, 0><<<(NPOST + 63) / 64, 256, 0, stream>>>(x_post, nullptr, Bpost, bp, hA[0], NPOST, 768);
  k_gemm64<0, 1, 0><<<(NUSER + 63) / 64, 256, 0, stream>>>(x_user, nullptr, Buser, bu, hA[1], NUSER, 32);
  k_gemm64<0, 1, 0><<<(NENT  + 63) / 64, 256, 0, stream>>>(x_ent,  nullptr, Bent,  be, hA[2], NENT, 64);

  // relation meta: publish u->p, repost u->p, contain p->e, interact u->u, follow u->u, similar p->p
  const int rsrc_t[6] = {1, 1, 0, 1, 1, 0};
  const int rdst_t[6] = {0, 0, 2, 1, 1, 0};
  const int rE[6]     = {100000, 200000, 200000, 400000, 400000, 250000};
  const int rfirst[6] = {1, 0, 1, 1, 0, 0};  // first relation writing each dst type

  float* cur[3] = {hA[0], hA[1], hA[2]};
  float* nxt[3] = {hB[0], hB[1], hB[2]};

  for (int l = 0; l < 2; l++){
    for (int r = 0; r < 6; r++){
      int st = rsrc_t[r], dt = rdst_t[r];
      int Ns = NN[st], Nd = NN[dt], E = rE[r];
      int m = l * 6 + r;
      int nmax = Ns > Nd ? Ns : Nd;
      k_al<<<(nmax + 255) / 256, 256, 0, stream>>>(cur[st], weff_s + m * 128, als, Ns,
                                                   cur[dt], weff_d + m * 128, ald, Nd);
      hipMemsetAsync(agg,  0, (size_t)Nd * 128 * 4, stream);
      hipMemsetAsync(sden, 0, (size_t)Nd * 2 * 4, stream);
      k_edge<<<(E + 3) / 4, 256, 0, stream>>>(esrc[r], edst[r], E, cur[st], als, ald, agg, sden);
      if (rfirst[r])
        k_gemm64<1, 0, 0><<<(Nd + 63) / 64, 256, 0, stream>>>(agg, sden, Bcomb + m * 8192, nullptr, nxt[dt], Nd, 128);
      else
        k_gemm64<1, 0, 1><<<(Nd + 63) / 64, 256, 0, stream>>>(agg, sden, Bcomb + m * 8192, nullptr, nxt[dt], Nd, 128);
    }
    k_bias_relu<<<(NPOST * 64 + 255) / 256, 256, 0, stream>>>(nxt[0], NPOST,
        gatb + (l * 6 + 0) * 64, gatb + (l * 6 + 1) * 64, gatb + (l * 6 + 5) * 64);
    k_bias_relu<<<(NUSER * 64 + 255) / 256, 256, 0, stream>>>(nxt[1], NUSER,
        gatb + (l * 6 + 3) * 64, gatb + (l * 6 + 4) * 64, nullptr);
    k_bias_relu<<<(NENT * 64 + 255) / 256, 256, 0, stream>>>(nxt[2], NENT,
        gatb + (l * 6 + 2) * 64, nullptr, nullptr);
    for (int i = 0; i < 3; i++){ float* tmp = cur[i]; cur[i] = nxt[i]; nxt[i] = tmp; }
  }

  k_classifier<<<(NPOST + 255) / 256, 256, 0, stream>>>(cur[0], cw1, cb1, cw2, cb2, out, NPOST);
}

// Round 2
// 1765.029 us; speedup vs baseline: 1.7508x; 1.7508x over previous
//
#include <hip/hip_runtime.h>

#define NPOST 100000
#define NUSER 50000
#define NENT  20000
#define NDTOT 420000          // concat node space over 6 relations (by dst type)
#define ETOT  1550000
#define NSCANBLK 206          // ceil(420000/2048)

struct EdgeMeta {
  const int* src[6];
  const int* dst[6];
  int E[6];
  int degoff[6];
};

// ---------------- prep kernels ----------------

// B[k*64+c] = W[c*K+k]   (W is [64,K] row-major -> B is [K,64])
__global__ void k_transpose64(const float* __restrict__ W, float* __restrict__ B, int K){
  int idx = blockIdx.x * blockDim.x + threadIdx.x;
  if (idx >= K * 64) return;
  int k = idx >> 6, c = idx & 63;
  B[idx] = W[c * K + k];
}

// Bstacked[q][hk*64+c] = W_src[m=QMAP[q], (hk/64)*64 + (hk%64 -> transposed)]
// q order: l0:{post:pub,repost,similar; user:interact,follow; ent:contain}, l1 same.
__global__ void k_prep_comb(const float* __restrict__ Wsrc, float* __restrict__ Bst){
  const int QMAP[12] = {0,1,5,3,4,2, 6,7,11,9,10,8};
  int idx = blockIdx.x * blockDim.x + threadIdx.x;
  if (idx >= 12 * 8192) return;
  int q = idx >> 13;
  int rem = idx & 8191;
  int hk = rem >> 6, c = rem & 63;
  int head = hk >> 6, k = hk & 63;
  int m = QMAP[q];
  Bst[idx] = Wsrc[m * 8192 + (head * 64 + c) * 64 + k];
}

// weff[m][h*64+k] = sum_c W[m, h*64+c, k] * a[m, h, c]
__global__ void k_weff(const float* __restrict__ W, const float* __restrict__ a,
                       float* __restrict__ weff){
  int idx = blockIdx.x * blockDim.x + threadIdx.x;
  if (idx >= 1536) return;
  int m = idx >> 7;
  int rem = idx & 127;
  int h = rem >> 6, k = rem & 63;
  const float* Wm = W + m * 8192;
  const float* am = a + m * 128;
  float acc = 0.f;
  #pragma unroll 8
  for (int c = 0; c < 64; c++)
    acc += Wm[(h * 64 + c) * 64 + k] * am[h * 64 + c];
  weff[idx] = acc;
}

// bsum[(l*3+t)*64+c] = sum of gat_b over relations feeding type t in layer l
__global__ void k_prep_bias(const float* __restrict__ gatb, float* __restrict__ bsum){
  int idx = blockIdx.x * blockDim.x + threadIdx.x;
  if (idx >= 384) return;
  int c = idx & 63;
  int lt = idx >> 6;        // 0..5
  int l = lt / 3, t = lt % 3;
  float v;
  if (t == 0)      v = gatb[(l*6+0)*64+c] + gatb[(l*6+1)*64+c] + gatb[(l*6+5)*64+c];
  else if (t == 1) v = gatb[(l*6+3)*64+c] + gatb[(l*6+4)*64+c];
  else             v = gatb[(l*6+2)*64+c];
  bsum[lt * 64 + c] = v;
}

// ---------------- CSR build ----------------

__global__ void k_hist(EdgeMeta em, int* __restrict__ deg){
  int r = blockIdx.y;
  int e = blockIdx.x * blockDim.x + threadIdx.x;
  if (e >= em.E[r]) return;
  atomicAdd(&deg[em.degoff[r] + em.dst[r][e]], 1);
}

__global__ __launch_bounds__(256) void k_scanA(const int* __restrict__ deg,
                                               int* __restrict__ rowstart,
                                               int* __restrict__ blocksum){
  __shared__ int sums[256];
  int t = threadIdx.x;
  int base = blockIdx.x * 2048 + t * 8;
  int v[8]; int s = 0;
  #pragma unroll
  for (int i = 0; i < 8; i++){
    int j = base + i;
    v[i] = (j < NDTOT) ? deg[j] : 0;
    s += v[i];
  }
  sums[t] = s;
  __syncthreads();
  for (int off = 1; off < 256; off <<= 1){
    int x = (t >= off) ? sums[t - off] : 0;
    __syncthreads();
    sums[t] += x;
    __syncthreads();
  }
  int excl = (t > 0) ? sums[t - 1] : 0;
  if (t == 255) blocksum[blockIdx.x] = sums[255];
  int run = excl;
  #pragma unroll
  for (int i = 0; i < 8; i++){
    int j = base + i;
    if (j < NDTOT) rowstart[j] = run;
    run += v[i];
  }
}

__global__ __launch_bounds__(256) void k_scanB(int* __restrict__ blocksum){
  __shared__ int s[256];
  int t = threadIdx.x;
  s[t] = (t < NSCANBLK) ? blocksum[t] : 0;
  __syncthreads();
  for (int off = 1; off < 256; off <<= 1){
    int x = (t >= off) ? s[t - off] : 0;
    __syncthreads();
    s[t] += x;
    __syncthreads();
  }
  int excl = (t > 0) ? s[t - 1] : 0;
  if (t < NSCANBLK) blocksum[t] = excl;
}

__global__ void k_scanC(int* __restrict__ rowstart, const int* __restrict__ blocksum){
  int j = blockIdx.x * blockDim.x + threadIdx.x;
  if (j < NDTOT) rowstart[j] += blocksum[j >> 11];
  if (j == 0) rowstart[NDTOT] = ETOT;
}

__global__ void k_scatter(EdgeMeta em, int* __restrict__ cursor, int* __restrict__ csr_src){
  int r = blockIdx.y;
  int e = blockIdx.x * blockDim.x + threadIdx.x;
  if (e >= em.E[r]) return;
  int d = em.dst[r][e];
  int pos = atomicAdd(&cursor[em.degoff[r] + d], 1);
  csr_src[pos] = em.src[r][e];
}

// ---------------- attention logits ----------------

static __device__ __forceinline__ void al_one(const float* __restrict__ hx,
                                              const float* __restrict__ w,
                                              float* __restrict__ out, int i){
  const float4* hr = (const float4*)(hx + (size_t)i * 64);
  const float4* w0 = (const float4*)w;
  const float4* w1 = (const float4*)(w + 64);
  float a0 = 0.f, a1 = 0.f;
  #pragma unroll
  for (int q = 0; q < 16; q++){
    float4 v = hr[q];
    float4 x0 = w0[q], x1 = w1[q];
    a0 += v.x*x0.x + v.y*x0.y + v.z*x0.z + v.w*x0.w;
    a1 += v.x*x1.x + v.y*x1.y + v.z*x1.z + v.w*x1.w;
  }
  out[i * 2]     = a0;
  out[i * 2 + 1] = a1;
}

__global__ void k_al(const float* __restrict__ hs, const float* __restrict__ ws,
                     float* __restrict__ als, int Ns,
                     const float* __restrict__ hd, const float* __restrict__ wd,
                     float* __restrict__ ald, int Nd){
  int i = blockIdx.x * blockDim.x + threadIdx.x;
  if (i < Ns) al_one(hs, ws, als, i);
  if (i < Nd) al_one(hd, wd, ald, i);
}

// ---------------- CSR aggregation: one wave per dst node, no atomics ----------------

__global__ __launch_bounds__(256) void k_agg(const int* __restrict__ rowstart,
                                             const int* __restrict__ csr_src,
                                             const float* __restrict__ h,
                                             const float* __restrict__ als,
                                             const float* __restrict__ ald,
                                             float* __restrict__ outp,
                                             int Nd, int ld, int degoff){
  int w = (blockIdx.x * blockDim.x + threadIdx.x) >> 6;
  int lane = threadIdx.x & 63;
  if (w >= Nd) return;
  int rs = rowstart[degoff + w];
  int re = rowstart[degoff + w + 1];
  float2 ad = *(const float2*)(ald + (size_t)w * 2);
  float a0 = 0.f, a1 = 0.f, s0 = 0.f, s1 = 0.f;
  for (int e = rs; e < re; e++){
    int sidx = csr_src[e];
    float2 as = *(const float2*)(als + (size_t)sidx * 2);
    float e0 = as.x + ad.x, e1 = as.y + ad.y;
    e0 = e0 > 0.f ? e0 : 0.2f * e0;
    e1 = e1 > 0.f ? e1 : 0.2f * e1;
    float p0 = __expf(e0), p1 = __expf(e1);
    float hv = h[(size_t)sidx * 64 + lane];
    a0 = fmaf(p0, hv, a0);
    a1 = fmaf(p1, hv, a1);
    s0 += p0; s1 += p1;
  }
  float r0 = s0 > 0.f ? 0.5f / s0 : 0.f;
  float r1 = s1 > 0.f ? 0.5f / s1 : 0.f;
  float* o = outp + (size_t)w * ld;
  o[lane]      = a0 * r0;
  o[64 + lane] = a1 * r1;
}

// ---------------- GEMM v2: C[N,64] = act(A[N,K] @ B[K,64] + bias) ----------------
// block 256, tile 64 rows x 64 cols, K-step 64. Thread (tx,ty) owns rows ty+16i, cols tx*4..+3.

template<int RELU>
__global__ __launch_bounds__(256) void k_gemm64(const float* __restrict__ A,
                                                const float* __restrict__ B,
                                                const float* __restrict__ bias,
                                                float* __restrict__ C, int N, int K){
  __shared__ float As[64][68];
  __shared__ float Bs[64][64];
  int t = threadIdx.x;
  int r0 = blockIdx.x * 64;
  int tx = t & 15, ty = t >> 4;
  float acc[4][4] = {};
  for (int k0 = 0; k0 < K; k0 += 64){
    #pragma unroll
    for (int i = 0; i < 4; i++){
      int f = t + i * 256;
      int row = f >> 4, kc = (f & 15) * 4;
      int gr = r0 + row, gk = k0 + kc;
      float4 v = {0.f, 0.f, 0.f, 0.f};
      if (gr < N && gk < K)
        v = *(const float4*)(A + (size_t)gr * K + gk);
      *(float4*)&As[row][kc] = v;
    }
    #pragma unroll
    for (int i = 0; i < 4; i++){
      int f = t + i * 256;
      int kk = f >> 4, c = (f & 15) * 4;
      float4 v = {0.f, 0.f, 0.f, 0.f};
      if (k0 + kk < K)
        v = *(const float4*)(B + (size_t)(k0 + kk) * 64 + c);
      *(float4*)&Bs[kk][c] = v;
    }
    __syncthreads();
    #pragma unroll
    for (int kk = 0; kk < 64; kk += 4){
      float4 a4[4], b4[4];
      #pragma unroll
      for (int i = 0; i < 4; i++) a4[i] = *(const float4*)&As[ty + 16 * i][kk];
      #pragma unroll
      for (int j = 0; j < 4; j++) b4[j] = *(const float4*)&Bs[kk + j][tx * 4];
      #pragma unroll
      for (int i = 0; i < 4; i++){
        float av[4] = {a4[i].x, a4[i].y, a4[i].z, a4[i].w};
        #pragma unroll
        for (int kj = 0; kj < 4; kj++){
          const float* bv = (const float*)&b4[kj];
          #pragma unroll
          for (int j = 0; j < 4; j++)
            acc[i][j] = fmaf(av[kj], bv[j], acc[i][j]);
        }
      }
    }
    __syncthreads();
  }
  float4 bb = *(const float4*)&bias[tx * 4];
  #pragma unroll
  for (int i = 0; i < 4; i++){
    int gr = r0 + ty + 16 * i;
    if (gr >= N) continue;
    float4 v;
    v.x = acc[i][0] + bb.x; v.y = acc[i][1] + bb.y;
    v.z = acc[i][2] + bb.z; v.w = acc[i][3] + bb.w;
    if (RELU){
      v.x = v.x > 0.f ? v.x : 0.f; v.y = v.y > 0.f ? v.y : 0.f;
      v.z = v.z > 0.f ? v.z : 0.f; v.w = v.w > 0.f ? v.w : 0.f;
    }
    *(float4*)&C[(size_t)gr * 64 + tx * 4] = v;
  }
}

// ---------------- classifier head ----------------

__global__ __launch_bounds__(256) void k_classifier(const float* __restrict__ hpost,
                                                    const float* __restrict__ w1,
                                                    const float* __restrict__ b1,
                                                    const float* __restrict__ w2,
                                                    const float* __restrict__ b2,
                                                    float* __restrict__ out, int N){
  __shared__ float w1s[32 * 64];
  __shared__ float b1s[32];
  __shared__ float w2s[32];
  for (int i = threadIdx.x; i < 2048; i += 256) w1s[i] = w1[i];
  if (threadIdx.x < 32){
    b1s[threadIdx.x] = b1[threadIdx.x];
    w2s[threadIdx.x] = w2[threadIdx.x];
  }
  __syncthreads();
  float bias2 = b2[0];
  for (int n = blockIdx.x * blockDim.x + threadIdx.x; n < N; n += gridDim.x * blockDim.x){
    float4 hr[16];
    const float4* hp = (const float4*)(hpost + (size_t)n * 64);
    #pragma unroll
    for (int q = 0; q < 16; q++) hr[q] = hp[q];
    float o = bias2;
    #pragma unroll 4
    for (int j = 0; j < 32; j++){
      float dacc = b1s[j];
      const float4* wr = (const float4*)(w1s + j * 64);
      #pragma unroll
      for (int q = 0; q < 16; q++){
        float4 w = wr[q]; float4 v = hr[q];
        dacc += w.x*v.x + w.y*v.y + w.z*v.z + w.w*v.w;
      }
      dacc = dacc > 0.f ? dacc : 0.f;
      o += w2s[j] * dacc;
    }
    out[n] = o;
  }
}

// ---------------- host ----------------

static inline size_t align256(size_t x){ return (x + 255) & ~(size_t)255; }

extern "C" void kernel_launch(void* const* d_in, const int* in_sizes, int n_in,
                              void* d_out, int out_size, void* d_ws, size_t ws_size,
                              hipStream_t stream){
  (void)in_sizes; (void)n_in; (void)out_size; (void)ws_size;
  const float* x_post = (const float*)d_in[0];
  const float* x_user = (const float*)d_in[1];
  const float* x_ent  = (const float*)d_in[2];
  EdgeMeta em;
  for (int r = 0; r < 6; r++){
    em.src[r] = (const int*)d_in[3 + 2*r];
    em.dst[r] = (const int*)d_in[4 + 2*r];
  }
  const int Earr[6]   = {100000, 200000, 200000, 400000, 400000, 250000};
  const int dgo[6]    = {0, 100000, 200000, 220000, 270000, 320000};
  for (int r = 0; r < 6; r++){ em.E[r] = Earr[r]; em.degoff[r] = dgo[r]; }

  const float* Wp   = (const float*)d_in[15]; const float* bp = (const float*)d_in[16];
  const float* Wu   = (const float*)d_in[17]; const float* bu = (const float*)d_in[18];
  const float* We   = (const float*)d_in[19]; const float* be = (const float*)d_in[20];
  const float* Wsrc = (const float*)d_in[21];
  const float* Wdst = (const float*)d_in[22];
  const float* asrc = (const float*)d_in[23];
  const float* adst = (const float*)d_in[24];
  const float* gatb = (const float*)d_in[25];
  const float* cw1  = (const float*)d_in[26]; const float* cb1 = (const float*)d_in[27];
  const float* cw2  = (const float*)d_in[28]; const float* cb2 = (const float*)d_in[29];
  float* out = (float*)d_out;

  const int NN[3] = {NPOST, NUSER, NENT};   // 0=post, 1=user, 2=entity

  // ---- workspace layout (~330 MB) ----
  char* p = (char*)d_ws;
  auto alloc = [&](size_t bytes){ char* r = p; p += align256(bytes); return r; };
  float* hA[3]; float* hB[3];
  for (int i = 0; i < 3; i++) hA[i] = (float*)alloc((size_t)NN[i] * 64 * 4);
  for (int i = 0; i < 3; i++) hB[i] = (float*)alloc((size_t)NN[i] * 64 * 4);
  float* als    = (float*)alloc((size_t)NPOST * 2 * 4);
  float* ald    = (float*)alloc((size_t)NPOST * 2 * 4);
  float* aggP   = (float*)alloc((size_t)NPOST * 384 * 4);
  float* aggU   = (float*)alloc((size_t)NUSER * 256 * 4);
  float* aggE   = (float*)alloc((size_t)NENT  * 128 * 4);
  float* weff_s = (float*)alloc(1536 * 4);
  float* weff_d = (float*)alloc(1536 * 4);
  float* Bpost  = (float*)alloc(768 * 64 * 4);
  float* Buser  = (float*)alloc(32 * 64 * 4);
  float* Bent   = (float*)alloc(64 * 64 * 4);
  float* Bst    = (float*)alloc(12 * 8192 * 4);
  float* bsum   = (float*)alloc(6 * 64 * 4);
  int* deg      = (int*)alloc((size_t)NDTOT * 4);
  int* rowstart = (int*)alloc((size_t)(NDTOT + 1) * 4);
  int* cursor   = (int*)alloc((size_t)NDTOT * 4);
  int* csr_src  = (int*)alloc((size_t)ETOT * 4);
  int* blocksum = (int*)alloc((size_t)NSCANBLK * 4);

  // ---- CSR build (edges are layer-invariant: build once) ----
  hipMemsetAsync(deg, 0, (size_t)NDTOT * 4, stream);
  k_hist<<<dim3(1563, 6), 256, 0, stream>>>(em, deg);
  k_scanA<<<NSCANBLK, 256, 0, stream>>>(deg, rowstart, blocksum);
  k_scanB<<<1, 256, 0, stream>>>(blocksum);
  k_scanC<<<(NDTOT + 255) / 256, 256, 0, stream>>>(rowstart, blocksum);
  hipMemcpyAsync(cursor, rowstart, (size_t)NDTOT * 4, hipMemcpyDeviceToDevice, stream);
  k_scatter<<<dim3(1563, 6), 256, 0, stream>>>(em, cursor, csr_src);

  // ---- weight prep ----
  k_transpose64<<<(768 * 64 + 255) / 256, 256, 0, stream>>>(Wp, Bpost, 768);
  k_transpose64<<<(32 * 64 + 255) / 256, 256, 0, stream>>>(Wu, Buser, 32);
  k_transpose64<<<(64 * 64 + 255) / 256, 256, 0, stream>>>(We, Bent, 64);
  k_prep_comb<<<(12 * 8192 + 255) / 256, 256, 0, stream>>>(Wsrc, Bst);
  k_weff<<<6, 256, 0, stream>>>(Wsrc, asrc, weff_s);
  k_weff<<<6, 256, 0, stream>>>(Wdst, adst, weff_d);
  k_prep_bias<<<2, 256, 0, stream>>>(gatb, bsum);

  // ---- input projections ----
  k_gemm64<0><<<(NPOST + 63) / 64, 256, 0, stream>>>(x_post, Bpost, bp, hA[0], NPOST, 768);
  k_gemm64<0><<<(NUSER + 63) / 64, 256, 0, stream>>>(x_user, Buser, bu, hA[1], NUSER, 32);
  k_gemm64<0><<<(NENT  + 63) / 64, 256, 0, stream>>>(x_ent,  Bent,  be, hA[2], NENT, 64);

  // relation meta: publish u->p, repost u->p, contain p->e, interact u->u, follow u->u, similar p->p
  const int rsrc_t[6] = {1, 1, 0, 1, 1, 0};
  const int rdst_t[6] = {0, 0, 2, 1, 1, 0};
  // slot of each relation within its dst-type stacked agg
  const int rslot[6]  = {0, 1, 0, 0, 1, 2};
  float* aggT[3] = {aggP, aggU, aggE};
  const int KT[3] = {384, 256, 128};

  float* cur[3] = {hA[0], hA[1], hA[2]};
  float* nxt[3] = {hB[0], hB[1], hB[2]};

  for (int l = 0; l < 2; l++){
    for (int r = 0; r < 6; r++){
      int st = rsrc_t[r], dt = rdst_t[r];
      int Ns = NN[st], Nd = NN[dt];
      int m = l * 6 + r;
      int nmax = Ns > Nd ? Ns : Nd;
      k_al<<<(nmax + 255) / 256, 256, 0, stream>>>(cur[st], weff_s + m * 128, als, Ns,
                                                   cur[dt], weff_d + m * 128, ald, Nd);
      k_agg<<<(Nd * 64 + 255) / 256, 256, 0, stream>>>(rowstart, csr_src, cur[st], als, ald,
                                                       aggT[dt] + rslot[r] * 128,
                                                       Nd, KT[dt], dgo[r]);
    }
    // one GEMM per dst type: K = stacked width, epilogue = summed bias + relu
    k_gemm64<1><<<(NPOST + 63) / 64, 256, 0, stream>>>(aggP, Bst + (size_t)(l*6+0)*8192,
                                                       bsum + (l*3+0)*64, nxt[0], NPOST, 384);
    k_gemm64<1><<<(NUSER + 63) / 64, 256, 0, stream>>>(aggU, Bst + (size_t)(l*6+3)*8192,
                                                       bsum + (l*3+1)*64, nxt[1], NUSER, 256);
    k_gemm64<1><<<(NENT  + 63) / 64, 256, 0, stream>>>(aggE, Bst + (size_t)(l*6+5)*8192,
                                                       bsum + (l*3+2)*64, nxt[2], NENT, 128);
    for (int i = 0; i < 3; i++){ float* tmp = cur[i]; cur[i] = nxt[i]; nxt[i] = tmp; }
  }

  k_classifier<<<(NPOST + 255) / 256, 256, 0, stream>>>(cur[0], cw1, cb1, cw2, cb2, out, NPOST);
}

// Round 3
// 1506.909 us; speedup vs baseline: 2.0507x; 1.1713x over previous
//
#include <hip/hip_runtime.h>

#define NPOST 100000
#define NUSER 50000
#define NENT  20000
#define NDTOT 420000
#define ETOT  1550000
#define NSCANBLK 206

typedef short short8 __attribute__((ext_vector_type(8)));
typedef float f32x4 __attribute__((ext_vector_type(4)));

static __device__ __forceinline__ unsigned short f2bf(float x){
  union { float f; unsigned u; } v; v.f = x;
  unsigned r = v.u + 0x7FFF + ((v.u >> 16) & 1);
  return (unsigned short)(r >> 16);
}
static __device__ __forceinline__ float bf2f(unsigned short h){
  union { unsigned u; float f; } v; v.u = ((unsigned)h) << 16;
  return v.f;
}

struct EdgeMeta {
  const int* src[6];
  const int* dst[6];
  int E[6];
  int degoff[6];
};

// ---------------- prep kernels ----------------

// split fp32 array into bf16 hi/lo planes (same layout)
__global__ void k_split(const float* __restrict__ X, unsigned short* __restrict__ H,
                        unsigned short* __restrict__ L, int n){
  int i = blockIdx.x * blockDim.x + threadIdx.x;
  if (i >= n) return;
  float x = X[i];
  unsigned short h = f2bf(x);
  H[i] = h;
  L[i] = f2bf(x - bf2f(h));
}

// layer-GEMM B planes: per (l,type) matrix Bt[64][K], Bt[n][k] = Wsrc[m][(head*64+n)*64+kk]
// where slot = k>>7, head = (k>>6)&1, kk = k&63; m = l*6 + relmap[type][slot]
__global__ void k_prep_layerB(const float* __restrict__ Wsrc,
                              unsigned short* __restrict__ H,
                              unsigned short* __restrict__ L){
  int idx = blockIdx.x * blockDim.x + threadIdx.x;
  if (idx >= 98304) return;
  const int off[6]  = {0, 24576, 40960, 49152, 73728, 90112};
  const int Ks[6]   = {384, 256, 128, 384, 256, 128};
  int seg = 5;
  #pragma unroll
  for (int s = 4; s >= 0; s--) if (idx < off[s + 1]) seg = s;
  int l = seg / 3, type = seg % 3;
  int K = Ks[seg];
  int rem = idx - off[seg];
  int n = rem / K, k = rem - n * K;
  int slot = k >> 7, head = (k >> 6) & 1, kk = k & 63;
  int rel;
  if (type == 0)      rel = (slot == 0) ? 0 : (slot == 1 ? 1 : 5);
  else if (type == 1) rel = (slot == 0) ? 3 : 4;
  else                rel = 2;
  int m = l * 6 + rel;
  float x = Wsrc[(size_t)m * 8192 + (head * 64 + n) * 64 + kk];
  unsigned short h = f2bf(x);
  H[idx] = h;
  L[idx] = f2bf(x - bf2f(h));
}

// weff[m][h*64+k] = sum_c W[m, h*64+c, k] * a[m, h, c]
__global__ void k_weff(const float* __restrict__ W, const float* __restrict__ a,
                       float* __restrict__ weff){
  int idx = blockIdx.x * blockDim.x + threadIdx.x;
  if (idx >= 1536) return;
  int m = idx >> 7;
  int rem = idx & 127;
  int h = rem >> 6, k = rem & 63;
  const float* Wm = W + m * 8192;
  const float* am = a + m * 128;
  float acc = 0.f;
  #pragma unroll 8
  for (int c = 0; c < 64; c++)
    acc += Wm[(h * 64 + c) * 64 + k] * am[h * 64 + c];
  weff[idx] = acc;
}

__global__ void k_prep_bias(const float* __restrict__ gatb, float* __restrict__ bsum){
  int idx = blockIdx.x * blockDim.x + threadIdx.x;
  if (idx >= 384) return;
  int c = idx & 63;
  int lt = idx >> 6;
  int l = lt / 3, t = lt % 3;
  float v;
  if (t == 0)      v = gatb[(l*6+0)*64+c] + gatb[(l*6+1)*64+c] + gatb[(l*6+5)*64+c];
  else if (t == 1) v = gatb[(l*6+3)*64+c] + gatb[(l*6+4)*64+c];
  else             v = gatb[(l*6+2)*64+c];
  bsum[lt * 64 + c] = v;
}

// ---------------- CSR build ----------------

__global__ void k_hist(EdgeMeta em, int* __restrict__ deg){
  int r = blockIdx.y;
  int e = blockIdx.x * blockDim.x + threadIdx.x;
  if (e >= em.E[r]) return;
  atomicAdd(&deg[em.degoff[r] + em.dst[r][e]], 1);
}

__global__ __launch_bounds__(256) void k_scanA(const int* __restrict__ deg,
                                               int* __restrict__ rowstart,
                                               int* __restrict__ blocksum){
  __shared__ int sums[256];
  int t = threadIdx.x;
  int base = blockIdx.x * 2048 + t * 8;
  int v[8]; int s = 0;
  #pragma unroll
  for (int i = 0; i < 8; i++){
    int j = base + i;
    v[i] = (j < NDTOT) ? deg[j] : 0;
    s += v[i];
  }
  sums[t] = s;
  __syncthreads();
  for (int off = 1; off < 256; off <<= 1){
    int x = (t >= off) ? sums[t - off] : 0;
    __syncthreads();
    sums[t] += x;
    __syncthreads();
  }
  int excl = (t > 0) ? sums[t - 1] : 0;
  if (t == 255) blocksum[blockIdx.x] = sums[255];
  int run = excl;
  #pragma unroll
  for (int i = 0; i < 8; i++){
    int j = base + i;
    if (j < NDTOT) rowstart[j] = run;
    run += v[i];
  }
}

__global__ __launch_bounds__(256) void k_scanB(int* __restrict__ blocksum){
  __shared__ int s[256];
  int t = threadIdx.x;
  s[t] = (t < NSCANBLK) ? blocksum[t] : 0;
  __syncthreads();
  for (int off = 1; off < 256; off <<= 1){
    int x = (t >= off) ? s[t - off] : 0;
    __syncthreads();
    s[t] += x;
    __syncthreads();
  }
  int excl = (t > 0) ? s[t - 1] : 0;
  if (t < NSCANBLK) blocksum[t] = excl;
}

__global__ void k_scanC(int* __restrict__ rowstart, const int* __restrict__ blocksum){
  int j = blockIdx.x * blockDim.x + threadIdx.x;
  if (j < NDTOT) rowstart[j] += blocksum[j >> 11];
  if (j == 0) rowstart[NDTOT] = ETOT;
}

__global__ void k_scatter(EdgeMeta em, int* __restrict__ cursor, int* __restrict__ csr_src){
  int r = blockIdx.y;
  int e = blockIdx.x * blockDim.x + threadIdx.x;
  if (e >= em.E[r]) return;
  int d = em.dst[r][e];
  int pos = atomicAdd(&cursor[em.degoff[r] + d], 1);
  csr_src[pos] = em.src[r][e];
}

// ---------------- attention logits ----------------

static __device__ __forceinline__ void al_one(const float* __restrict__ hx,
                                              const float* __restrict__ w,
                                              float* __restrict__ out, int i){
  const float4* hr = (const float4*)(hx + (size_t)i * 64);
  const float4* w0 = (const float4*)w;
  const float4* w1 = (const float4*)(w + 64);
  float a0 = 0.f, a1 = 0.f;
  #pragma unroll
  for (int q = 0; q < 16; q++){
    float4 v = hr[q];
    float4 x0 = w0[q], x1 = w1[q];
    a0 += v.x*x0.x + v.y*x0.y + v.z*x0.z + v.w*x0.w;
    a1 += v.x*x1.x + v.y*x1.y + v.z*x1.z + v.w*x1.w;
  }
  out[i * 2]     = a0;
  out[i * 2 + 1] = a1;
}

__global__ void k_al(const float* __restrict__ hs, const float* __restrict__ ws,
                     float* __restrict__ als, int Ns,
                     const float* __restrict__ hd, const float* __restrict__ wd,
                     float* __restrict__ ald, int Nd){
  int i = blockIdx.x * blockDim.x + threadIdx.x;
  if (i < Ns) al_one(hs, ws, als, i);
  if (i < Nd) al_one(hd, wd, ald, i);
}

// ---------------- CSR aggregation -> split bf16 planes ----------------

__global__ __launch_bounds__(256) void k_agg(const int* __restrict__ rowstart,
                                             const int* __restrict__ csr_src,
                                             const float* __restrict__ h,
                                             const float* __restrict__ als,
                                             const float* __restrict__ ald,
                                             unsigned short* __restrict__ aggH,
                                             unsigned short* __restrict__ aggL,
                                             int Nd, int K, int degoff){
  int w = (blockIdx.x * blockDim.x + threadIdx.x) >> 6;
  int lane = threadIdx.x & 63;
  if (w >= Nd) return;
  int rs = rowstart[degoff + w];
  int re = rowstart[degoff + w + 1];
  float2 ad = *(const float2*)(ald + (size_t)w * 2);
  float a0 = 0.f, a1 = 0.f, s0 = 0.f, s1 = 0.f;
  for (int e = rs; e < re; e++){
    int sidx = csr_src[e];
    float2 as = *(const float2*)(als + (size_t)sidx * 2);
    float e0 = as.x + ad.x, e1 = as.y + ad.y;
    e0 = e0 > 0.f ? e0 : 0.2f * e0;
    e1 = e1 > 0.f ? e1 : 0.2f * e1;
    float p0 = __expf(e0), p1 = __expf(e1);
    float hv = h[(size_t)sidx * 64 + lane];
    a0 = fmaf(p0, hv, a0);
    a1 = fmaf(p1, hv, a1);
    s0 += p0; s1 += p1;
  }
  float r0 = s0 > 0.f ? 0.5f / s0 : 0.f;
  float r1 = s1 > 0.f ? 0.5f / s1 : 0.f;
  float v0 = a0 * r0, v1 = a1 * r1;
  size_t base = (size_t)w * K;
  unsigned short h0 = f2bf(v0);
  unsigned short h1 = f2bf(v1);
  aggH[base + lane]      = h0;
  aggH[base + 64 + lane] = h1;
  aggL[base + lane]      = f2bf(v0 - bf2f(h0));
  aggL[base + 64 + lane] = f2bf(v1 - bf2f(h1));
}

// ---------------- MFMA GEMM: C[N,64] = act(A[N,K] @ Bt^T + bias) ----------------
// Bt is [64 n][K k] split bf16 (hi/lo). A: ASRC=0 fp32 row-major (split in-register),
// ASRC=1 pre-split bf16 hi/lo planes [N][K].
// Tile 128 rows x 64 cols, K-chunk 32, 4 waves; 16x16x32 bf16 MFMA, 3-MFMA split product.
// LDS XOR swizzle: element (row,k) at row*32 + (((k>>3)^((row>>2)&3))<<3) + (k&7).

static __device__ __forceinline__ int swz(int row, int k){
  return row * 32 + ((((k >> 3) ^ ((row >> 2) & 3))) << 3) + (k & 7);
}

template<int ASRC, int RELU>
__global__ __launch_bounds__(256) void k_mfgemm(const float* __restrict__ A32,
                                                const unsigned short* __restrict__ AH,
                                                const unsigned short* __restrict__ AL,
                                                const unsigned short* __restrict__ BH,
                                                const unsigned short* __restrict__ BL,
                                                const float* __restrict__ bias,
                                                float* __restrict__ C, int N, int K){
  __shared__ __align__(16) unsigned short sAh[128 * 32];
  __shared__ __align__(16) unsigned short sAl[128 * 32];
  __shared__ __align__(16) unsigned short sBh[64 * 32];
  __shared__ __align__(16) unsigned short sBl[64 * 32];
  int t = threadIdx.x;
  int w = t >> 6, lane = t & 63;
  int q = lane >> 4, m15 = lane & 15;
  int r0 = blockIdx.x * 128;
  f32x4 acc[2][4];
  #pragma unroll
  for (int i = 0; i < 2; i++)
    #pragma unroll
    for (int j = 0; j < 4; j++)
      acc[i][j] = (f32x4){0.f, 0.f, 0.f, 0.f};

  int arow = t >> 1, akb = (t & 1) * 16;
  int brow = t >> 2, bkb = (t & 3) * 8;

  for (int k0 = 0; k0 < K; k0 += 32){
    // ---- stage A ----
    int gr = r0 + arow;
    if (ASRC == 0){
      float v[16];
      if (gr < N){
        const float4* ap = (const float4*)(A32 + (size_t)gr * K + k0 + akb);
        #pragma unroll
        for (int i = 0; i < 4; i++){
          float4 f = ap[i];
          v[i*4+0] = f.x; v[i*4+1] = f.y; v[i*4+2] = f.z; v[i*4+3] = f.w;
        }
      } else {
        #pragma unroll
        for (int i = 0; i < 16; i++) v[i] = 0.f;
      }
      short8 h0, h1, l0, l1;
      #pragma unroll
      for (int i = 0; i < 8; i++){
        unsigned short hh = f2bf(v[i]);
        h0[i] = (short)hh; l0[i] = (short)f2bf(v[i] - bf2f(hh));
        unsigned short hj = f2bf(v[8+i]);
        h1[i] = (short)hj; l1[i] = (short)f2bf(v[8+i] - bf2f(hj));
      }
      *(short8*)(sAh + swz(arow, akb))     = h0;
      *(short8*)(sAh + swz(arow, akb + 8)) = h1;
      *(short8*)(sAl + swz(arow, akb))     = l0;
      *(short8*)(sAl + swz(arow, akb + 8)) = l1;
    } else {
      short8 h0 = {0,0,0,0,0,0,0,0}, h1 = {0,0,0,0,0,0,0,0};
      short8 l0 = {0,0,0,0,0,0,0,0}, l1 = {0,0,0,0,0,0,0,0};
      if (gr < N){
        const short8* hp = (const short8*)(AH + (size_t)gr * K + k0 + akb);
        const short8* lp = (const short8*)(AL + (size_t)gr * K + k0 + akb);
        h0 = hp[0]; h1 = hp[1];
        l0 = lp[0]; l1 = lp[1];
      }
      *(short8*)(sAh + swz(arow, akb))     = h0;
      *(short8*)(sAh + swz(arow, akb + 8)) = h1;
      *(short8*)(sAl + swz(arow, akb))     = l0;
      *(short8*)(sAl + swz(arow, akb + 8)) = l1;
    }
    // ---- stage B ----
    {
      short8 bh = *(const short8*)(BH + (size_t)brow * K + k0 + bkb);
      short8 bl = *(const short8*)(BL + (size_t)brow * K + k0 + bkb);
      *(short8*)(sBh + swz(brow, bkb)) = bh;
      *(short8*)(sBl + swz(brow, bkb)) = bl;
    }
    __syncthreads();
    // ---- fragments + MFMA ----
    short8 ah[2], al_[2];
    #pragma unroll
    for (int i = 0; i < 2; i++){
      int mrow = w * 32 + i * 16 + m15;
      ah[i]  = *(const short8*)(sAh + swz(mrow, q * 8));
      al_[i] = *(const short8*)(sAl + swz(mrow, q * 8));
    }
    #pragma unroll
    for (int j = 0; j < 4; j++){
      int bn = j * 16 + m15;
      short8 bh = *(const short8*)(sBh + swz(bn, q * 8));
      short8 bl = *(const short8*)(sBl + swz(bn, q * 8));
      #pragma unroll
      for (int i = 0; i < 2; i++){
        acc[i][j] = __builtin_amdgcn_mfma_f32_16x16x32_bf16(ah[i],  bh, acc[i][j], 0, 0, 0);
        acc[i][j] = __builtin_amdgcn_mfma_f32_16x16x32_bf16(ah[i],  bl, acc[i][j], 0, 0, 0);
        acc[i][j] = __builtin_amdgcn_mfma_f32_16x16x32_bf16(al_[i], bh, acc[i][j], 0, 0, 0);
      }
    }
    __syncthreads();
  }
  // ---- epilogue ----
  #pragma unroll
  for (int j = 0; j < 4; j++){
    int col = j * 16 + m15;
    float bv = bias[col];
    #pragma unroll
    for (int i = 0; i < 2; i++){
      #pragma unroll
      for (int r = 0; r < 4; r++){
        int row = r0 + w * 32 + i * 16 + q * 4 + r;
        if (row < N){
          float vv = acc[i][j][r] + bv;
          if (RELU) vv = vv > 0.f ? vv : 0.f;
          C[(size_t)row * 64 + col] = vv;
        }
      }
    }
  }
}

// ---------------- classifier head ----------------

__global__ __launch_bounds__(256) void k_classifier(const float* __restrict__ hpost,
                                                    const float* __restrict__ w1,
                                                    const float* __restrict__ b1,
                                                    const float* __restrict__ w2,
                                                    const float* __restrict__ b2,
                                                    float* __restrict__ out, int N){
  __shared__ float w1s[32 * 64];
  __shared__ float b1s[32];
  __shared__ float w2s[32];
  for (int i = threadIdx.x; i < 2048; i += 256) w1s[i] = w1[i];
  if (threadIdx.x < 32){
    b1s[threadIdx.x] = b1[threadIdx.x];
    w2s[threadIdx.x] = w2[threadIdx.x];
  }
  __syncthreads();
  float bias2 = b2[0];
  for (int n = blockIdx.x * blockDim.x + threadIdx.x; n < N; n += gridDim.x * blockDim.x){
    float4 hr[16];
    const float4* hp = (const float4*)(hpost + (size_t)n * 64);
    #pragma unroll
    for (int q = 0; q < 16; q++) hr[q] = hp[q];
    float o = bias2;
    #pragma unroll 4
    for (int j = 0; j < 32; j++){
      float dacc = b1s[j];
      const float4* wr = (const float4*)(w1s + j * 64);
      #pragma unroll
      for (int q = 0; q < 16; q++){
        float4 w = wr[q]; float4 v = hr[q];
        dacc += w.x*v.x + w.y*v.y + w.z*v.z + w.w*v.w;
      }
      dacc = dacc > 0.f ? dacc : 0.f;
      o += w2s[j] * dacc;
    }
    out[n] = o;
  }
}

// ---------------- host ----------------

static inline size_t align256(size_t x){ return (x + 255) & ~(size_t)255; }

extern "C" void kernel_launch(void* const* d_in, const int* in_sizes, int n_in,
                              void* d_out, int out_size, void* d_ws, size_t ws_size,
                              hipStream_t stream){
  (void)in_sizes; (void)n_in; (void)out_size; (void)ws_size;
  const float* x_post = (const float*)d_in[0];
  const float* x_user = (const float*)d_in[1];
  const float* x_ent  = (const float*)d_in[2];
  EdgeMeta em;
  for (int r = 0; r < 6; r++){
    em.src[r] = (const int*)d_in[3 + 2*r];
    em.dst[r] = (const int*)d_in[4 + 2*r];
  }
  const int Earr[6] = {100000, 200000, 200000, 400000, 400000, 250000};
  const int dgo[6]  = {0, 100000, 200000, 220000, 270000, 320000};
  for (int r = 0; r < 6; r++){ em.E[r] = Earr[r]; em.degoff[r] = dgo[r]; }

  const float* Wp   = (const float*)d_in[15]; const float* bp = (const float*)d_in[16];
  const float* Wu   = (const float*)d_in[17]; const float* bu = (const float*)d_in[18];
  const float* We   = (const float*)d_in[19]; const float* be = (const float*)d_in[20];
  const float* Wsrc = (const float*)d_in[21];
  const float* Wdst = (const float*)d_in[22];
  const float* asrc = (const float*)d_in[23];
  const float* adst = (const float*)d_in[24];
  const float* gatb = (const float*)d_in[25];
  const float* cw1  = (const float*)d_in[26]; const float* cb1 = (const float*)d_in[27];
  const float* cw2  = (const float*)d_in[28]; const float* cb2 = (const float*)d_in[29];
  float* out = (float*)d_out;

  const int NN[3] = {NPOST, NUSER, NENT};

  // ---- workspace ----
  char* p = (char*)d_ws;
  auto alloc = [&](size_t bytes){ char* r = p; p += align256(bytes); return r; };
  float* hA[3]; float* hB[3];
  for (int i = 0; i < 3; i++) hA[i] = (float*)alloc((size_t)NN[i] * 64 * 4);
  for (int i = 0; i < 3; i++) hB[i] = (float*)alloc((size_t)NN[i] * 64 * 4);
  float* als = (float*)alloc((size_t)NPOST * 2 * 4);
  float* ald = (float*)alloc((size_t)NPOST * 2 * 4);
  unsigned short* aggHT[3]; unsigned short* aggLT[3];
  const int KT[3] = {384, 256, 128};
  for (int i = 0; i < 3; i++) aggHT[i] = (unsigned short*)alloc((size_t)NN[i] * KT[i] * 2);
  for (int i = 0; i < 3; i++) aggLT[i] = (unsigned short*)alloc((size_t)NN[i] * KT[i] * 2);
  float* weff_s = (float*)alloc(1536 * 4);
  float* weff_d = (float*)alloc(1536 * 4);
  unsigned short* WpH = (unsigned short*)alloc(768 * 64 * 2);
  unsigned short* WpL = (unsigned short*)alloc(768 * 64 * 2);
  unsigned short* WuH = (unsigned short*)alloc(32 * 64 * 2);
  unsigned short* WuL = (unsigned short*)alloc(32 * 64 * 2);
  unsigned short* WeH = (unsigned short*)alloc(64 * 64 * 2);
  unsigned short* WeL = (unsigned short*)alloc(64 * 64 * 2);
  unsigned short* lbH = (unsigned short*)alloc(98304 * 2);
  unsigned short* lbL = (unsigned short*)alloc(98304 * 2);
  float* bsum   = (float*)alloc(6 * 64 * 4);
  int* deg      = (int*)alloc((size_t)NDTOT * 4);
  int* rowstart = (int*)alloc((size_t)(NDTOT + 1) * 4);
  int* cursor   = (int*)alloc((size_t)NDTOT * 4);
  int* csr_src  = (int*)alloc((size_t)ETOT * 4);
  int* blocksum = (int*)alloc((size_t)NSCANBLK * 4);

  // ---- CSR build (layer-invariant) ----
  hipMemsetAsync(deg, 0, (size_t)NDTOT * 4, stream);
  k_hist<<<dim3(1563, 6), 256, 0, stream>>>(em, deg);
  k_scanA<<<NSCANBLK, 256, 0, stream>>>(deg, rowstart, blocksum);
  k_scanB<<<1, 256, 0, stream>>>(blocksum);
  k_scanC<<<(NDTOT + 255) / 256, 256, 0, stream>>>(rowstart, blocksum);
  hipMemcpyAsync(cursor, rowstart, (size_t)NDTOT * 4, hipMemcpyDeviceToDevice, stream);
  k_scatter<<<dim3(1563, 6), 256, 0, stream>>>(em, cursor, csr_src);

  // ---- weight prep ----
  k_split<<<192, 256, 0, stream>>>(Wp, WpH, WpL, 768 * 64);
  k_split<<<8,   256, 0, stream>>>(Wu, WuH, WuL, 32 * 64);
  k_split<<<16,  256, 0, stream>>>(We, WeH, WeL, 64 * 64);
  k_prep_layerB<<<384, 256, 0, stream>>>(Wsrc, lbH, lbL);
  k_weff<<<6, 256, 0, stream>>>(Wsrc, asrc, weff_s);
  k_weff<<<6, 256, 0, stream>>>(Wdst, adst, weff_d);
  k_prep_bias<<<2, 256, 0, stream>>>(gatb, bsum);

  // ---- input projections (MFMA) ----
  k_mfgemm<0, 0><<<(NPOST + 127) / 128, 256, 0, stream>>>(x_post, nullptr, nullptr, WpH, WpL, bp, hA[0], NPOST, 768);
  k_mfgemm<0, 0><<<(NUSER + 127) / 128, 256, 0, stream>>>(x_user, nullptr, nullptr, WuH, WuL, bu, hA[1], NUSER, 32);
  k_mfgemm<0, 0><<<(NENT  + 127) / 128, 256, 0, stream>>>(x_ent,  nullptr, nullptr, WeH, WeL, be, hA[2], NENT, 64);

  const int rsrc_t[6] = {1, 1, 0, 1, 1, 0};
  const int rdst_t[6] = {0, 0, 2, 1, 1, 0};
  const int rslot[6]  = {0, 1, 0, 0, 1, 2};
  const int segoff[6] = {0, 24576, 40960, 49152, 73728, 90112};  // (l,type) B offsets

  float* cur[3] = {hA[0], hA[1], hA[2]};
  float* nxt[3] = {hB[0], hB[1], hB[2]};

  for (int l = 0; l < 2; l++){
    for (int r = 0; r < 6; r++){
      int st = rsrc_t[r], dt = rdst_t[r];
      int Ns = NN[st], Nd = NN[dt];
      int m = l * 6 + r;
      int nmax = Ns > Nd ? Ns : Nd;
      k_al<<<(nmax + 255) / 256, 256, 0, stream>>>(cur[st], weff_s + m * 128, als, Ns,
                                                   cur[dt], weff_d + m * 128, ald, Nd);
      k_agg<<<(Nd * 64 + 255) / 256, 256, 0, stream>>>(rowstart, csr_src, cur[st], als, ald,
                                                       aggHT[dt] + rslot[r] * 128,
                                                       aggLT[dt] + rslot[r] * 128,
                                                       Nd, KT[dt], dgo[r]);
    }
    for (int ty = 0; ty < 3; ty++){
      k_mfgemm<1, 1><<<(NN[ty] + 127) / 128, 256, 0, stream>>>(
          nullptr, aggHT[ty], aggLT[ty],
          lbH + segoff[l * 3 + ty], lbL + segoff[l * 3 + ty],
          bsum + (l * 3 + ty) * 64, nxt[ty], NN[ty], KT[ty]);
    }
    for (int i = 0; i < 3; i++){ float* tmp = cur[i]; cur[i] = nxt[i]; nxt[i] = tmp; }
  }

  k_classifier<<<(NPOST + 255) / 256, 256, 0, stream>>>(cur[0], cw1, cb1, cw2, cb2, out, NPOST);
}